// Round 4
// baseline (868.082 us; speedup 1.0000x reference)
//
#include <hip/hip_runtime.h>

using u16 = unsigned short;
using f32x4 = __attribute__((ext_vector_type(4))) float;
using s16x8 = __attribute__((ext_vector_type(8))) short;

// ---- problem constants (T=512, B=64, D=256, H=256) ----
#define TT 512
#define BB 64
// output element offsets (FP32 elements) in d_out, concatenated return order:
// spikes [513,64,256], preds [512,64,256], probs [512,64,256], v_T [64,256], s_T [64,256]
#define SPIKES_OFF 0L
#define PREDS_OFF  8404992L
#define PROBS_OFF  16793600L
#define VT_OFF     25182208L
#define ST_OFF     25198592L

__device__ __forceinline__ u16 f2bf(float f) {
    union { float f; unsigned int i; } cv; cv.f = f;
    unsigned int x = cv.i;
    return (u16)((x + 0x7FFFu + ((x >> 16) & 1u)) >> 16);   // RNE
}

// ---------------------------------------------------------------------------
// GEMM: C[m][n] = sum_k A[m][k] * W[k][n].  A fp32, W fp32 (both converted to
// bf16 for MFMA), C fp32.  M=32768, K=N=256.
// Swapped-operand MFMA: A_op = W^T (regs), B_op = A rows (LDS, bf16).
// Lane holds D[col=l15 -> m][row=quad*4+r -> n]; 4 consecutive n -> float4 store.
// wg: 256 thr = 4 waves; wg tile M=64 (all N=256); wave w -> n in [w*64,w*64+64).
// ---------------------------------------------------------------------------
__global__ __launch_bounds__(256, 2)
void gemm_rows(const float* __restrict__ A, const float* __restrict__ W,
               float* __restrict__ C)
{
    const int tid  = threadIdx.x;
    const int lane = tid & 63;
    const int wave = tid >> 6;
    const int l15  = lane & 15;
    const int quad = lane >> 4;
    const long mblock = (long)blockIdx.x * 64;

    __shared__ u16 Alds[64][264];   // bf16 tile, +8 pad per row

    // stage A tile: 64 rows x 256 fp32, convert to bf16 (16 x 256 x f32x4)
    #pragma unroll
    for (int i = 0; i < 16; ++i) {
        int q = i*256 + tid;
        int r = q >> 6;
        int c = (q & 63) << 2;             // element col
        f32x4 a4 = *(const f32x4*)&A[(mblock + r)*256 + c];
        unsigned int b0 = f2bf(a4[0]), b1 = f2bf(a4[1]);
        unsigned int b2 = f2bf(a4[2]), b3 = f2bf(a4[3]);
        uint2 val; val.x = b0 | (b1 << 16); val.y = b2 | (b3 << 16);
        *(uint2*)&Alds[r][c] = val;
    }

    // W^T fragments: lane holds bf16(W[k][n]) for n = nbase+nt*16+l15,
    // k = kt*32 + quad*8 + j.  Scalar fp32 loads; W is 256 KB (L2-resident).
    s16x8 wfrag[4][8];
    const int nbase = wave * 64;
    #pragma unroll
    for (int nt = 0; nt < 4; ++nt) {
        const int n = nbase + nt*16 + l15;
        #pragma unroll
        for (int kt = 0; kt < 8; ++kt) {
            const int kb = kt*32 + quad*8;
            union { short s[8]; s16x8 v; } f;
            #pragma unroll
            for (int j = 0; j < 8; ++j)
                f.s[j] = (short)f2bf(W[(kb + j)*256 + n]);
            wfrag[nt][kt] = f.v;
        }
    }

    __syncthreads();

    f32x4 acc[4][4] = {};   // [mt][nt]
    #pragma unroll
    for (int kt = 0; kt < 8; ++kt) {
        s16x8 xfrag[4];
        #pragma unroll
        for (int mt = 0; mt < 4; ++mt)
            xfrag[mt] = *(const s16x8*)&Alds[mt*16 + l15][kt*32 + quad*8];
        #pragma unroll
        for (int mt = 0; mt < 4; ++mt)
            #pragma unroll
            for (int nt = 0; nt < 4; ++nt)
                acc[mt][nt] = __builtin_amdgcn_mfma_f32_16x16x32_bf16(
                    wfrag[nt][kt], xfrag[mt], acc[mt][nt], 0, 0, 0);
    }

    #pragma unroll
    for (int mt = 0; mt < 4; ++mt) {
        long m = mblock + mt*16 + l15;
        #pragma unroll
        for (int nt = 0; nt < 4; ++nt) {
            int n = nbase + nt*16 + quad*4;
            *(f32x4*)&C[m*256 + n] = acc[mt][nt];   // 16B aligned
        }
    }
}

// ---------------------------------------------------------------------------
// Sequential recurrence. One wg per batch row (64 wgs x 256 thr).
// Thread h keeps W_rec[:,h] in 256 fp32 VGPRs (column read W_rec[k*256+h] is
// coalesced across h). Everything fp32.
//   v = 0.9 v + Xin[t,b,h] + b_h + dot(s, w);  s = sigmoid(v)
// Writes spikes[0]=spike0, spikes[t+1] == probs[t] (spike==prob), v_T, s_T.
// ---------------------------------------------------------------------------
__global__ __launch_bounds__(256, 1)
void recurrence(const float* __restrict__ Xin, const float* __restrict__ spike0,
                const float* __restrict__ v0, const float* __restrict__ Wrec,
                const float* __restrict__ bvec, float* __restrict__ out)
{
    const int b = blockIdx.x;
    const int h = threadIdx.x;

    float w[256];
    #pragma unroll
    for (int k = 0; k < 256; ++k)
        w[k] = Wrec[k*256 + h];           // coalesced across lanes

    __shared__ float s_lds[256];
    const float s0 = spike0[b*256 + h];
    s_lds[h] = s0;
    out[SPIKES_OFF + b*256 + h] = s0;           // spikes[0] = spike0
    float v = v0[b*256 + h];
    const float bias = bvec[h];
    __syncthreads();

    float xin_c = Xin[(long)b*256 + h];         // t=0 prefetched
    for (int t = 0; t < TT; ++t) {
        const int tn = (t + 1 < TT) ? t + 1 : TT - 1;
        const float xin_n = Xin[((long)tn*BB + b)*256 + h];   // prefetch next t

        float a0 = 0.f, a1 = 0.f, a2 = 0.f, a3 = 0.f;
        #pragma unroll
        for (int k = 0; k < 256; k += 8) {
            f32x4 sA = *(const f32x4*)&s_lds[k];      // same-addr broadcast reads
            f32x4 sB = *(const f32x4*)&s_lds[k + 4];
            a0 = fmaf(sA[0], w[k+0], a0);
            a1 = fmaf(sA[1], w[k+1], a1);
            a2 = fmaf(sA[2], w[k+2], a2);
            a3 = fmaf(sA[3], w[k+3], a3);
            a0 = fmaf(sB[0], w[k+4], a0);
            a1 = fmaf(sB[1], w[k+5], a1);
            a2 = fmaf(sB[2], w[k+6], a2);
            a3 = fmaf(sB[3], w[k+7], a3);
        }
        v = 0.9f*v + xin_c + bias + ((a0 + a1) + (a2 + a3));
        const float prob = 1.0f / (1.0f + __expf(-v));

        __syncthreads();                 // everyone done reading old s
        s_lds[h] = prob;

        const long o = (long)t*16384 + b*256 + h;
        out[SPIKES_OFF + o + 16384] = prob;   // spikes[t+1]
        out[PROBS_OFF  + o]         = prob;   // probs[t] (spike == prob)
        xin_c = xin_n;
        __syncthreads();                 // new s visible before next dot
    }
    out[VT_OFF + b*256 + h] = v;
    out[ST_OFF + b*256 + h] = s_lds[h];   // s_T = last spike
}

// ---------------------------------------------------------------------------
extern "C" void kernel_launch(void* const* d_in, const int* in_sizes, int n_in,
                              void* d_out, int out_size, void* d_ws, size_t ws_size,
                              hipStream_t stream) {
    // Inputs fp32 (reference dtypes); OUTPUT IS FP32 (round-3 evidence:
    // output-0 absmax 3.46 > 1 is impossible for bf16-written sigmoids —
    // the fp32 chunk boundaries put staged Xin inside the spikes chunk).
    const float* inputs = (const float*)d_in[0];   // [512,64,256]
    const float* spike0 = (const float*)d_in[1];   // [64,256]
    const float* v0     = (const float*)d_in[2];   // [64,256]
    const float* W_in   = (const float*)d_in[3];   // [256,256]
    const float* W_rec  = (const float*)d_in[4];   // [256,256]
    const float* W_out  = (const float*)d_in[5];   // [256,256]
    const float* bvec   = (const float*)d_in[6];   // [256]
    float* out = (float*)d_out;

    // No d_ws: Xin (fp32 [32768,256] = 8,388,608 floats) is staged in the
    // preds output region (identical element count), consumed by the
    // recurrence, then overwritten by gemm2 with the real preds.
    float* Xin = out + PREDS_OFF;

    // Xin[t*64+b][h] = inputs[t,b,:] @ W_in  (bias folded into recurrence)
    gemm_rows<<<512, 256, 0, stream>>>(inputs, W_in, Xin);
    recurrence<<<64, 256, 0, stream>>>(Xin, spike0, v0, W_rec, bvec, out);
    // preds[t,b,:] = spikes[t+1,b,:] @ W_out  (reads spikes region, overwrites Xin)
    gemm_rows<<<512, 256, 0, stream>>>(out + 16384, W_out, out + PREDS_OFF);
}